// Round 2
// baseline (284.443 us; speedup 1.0000x reference)
//
#include <hip/hip_runtime.h>
#include <hip/hip_bf16.h>
#include <math.h>

#define N_TOT 8192
#define HALF_N 4096
#define D_DIM 512
#define BM 256         // tile edge (256x256 tiles)
#define BK 64          // fp8 bytes per K-chunk; 8 K-iterations, 64B LDS rows
#define NKIT (D_DIM / BK)
#define NTILES 528     // 32*33/2 upper-triangle 256x256 tiles
#define THREADS 512    // 8 waves

typedef float f32x4_t __attribute__((ext_vector_type(4)));
typedef long long i64x2 __attribute__((ext_vector_type(2)));

typedef __attribute__((address_space(1))) unsigned int g_u32;
typedef __attribute__((address_space(3))) unsigned int l_u32;

// Kernel 1: L2-normalize rows of [p1;p2] -> fp8 e4m3 Z in k-PERMUTED layout
// (validated R9/R11): within each 64B k-block, source byte k (q=(k>>3)&3,
// h=(k>>5)&1) stored at q*16 + h*8 + (k&7). Both GEMM operands use the same
// bijection, so dot products are unaffected; a lane's two 8B MFMA k-pieces
// are one contiguous 16B chunk -> single ds_read_b128, zero bank conflicts.
__global__ __launch_bounds__(256) void k_normalize(
    const float* __restrict__ p1, const float* __restrict__ p2,
    unsigned char* __restrict__ zf8, float* __restrict__ rowsum,
    float* __restrict__ out)
{
    const int w = threadIdx.x >> 6;
    const int lane = threadIdx.x & 63;
    const int row = blockIdx.x * 4 + w;

    if (threadIdx.x < 4) rowsum[blockIdx.x * 4 + threadIdx.x] = 0.0f;
    if (blockIdx.x == 0 && threadIdx.x == 0) out[0] = 0.0f;

    const float* src = (row < HALF_N) ? p1 + (size_t)row * D_DIM
                                      : p2 + (size_t)(row - HALF_N) * D_DIM;
    float4 a = *(const float4*)(src + lane * 4);
    float4 b = *(const float4*)(src + 256 + lane * 4);
    float s = a.x*a.x + a.y*a.y + a.z*a.z + a.w*a.w
            + b.x*b.x + b.y*b.y + b.z*b.z + b.w*b.w;
    #pragma unroll
    for (int m = 1; m < 64; m <<= 1) s += __shfl_xor(s, m, 64);
    float inv = 1.0f / fmaxf(sqrtf(s), 1e-8f);

    int pk0 = __builtin_amdgcn_cvt_pk_fp8_f32(a.x * inv, a.y * inv, 0, false);
    pk0     = __builtin_amdgcn_cvt_pk_fp8_f32(a.z * inv, a.w * inv, pk0, true);
    int pk1 = __builtin_amdgcn_cvt_pk_fp8_f32(b.x * inv, b.y * inv, 0, false);
    pk1     = __builtin_amdgcn_cvt_pk_fp8_f32(b.z * inv, b.w * inv, pk1, true);

    unsigned char* dst = zf8 + (size_t)row * D_DIM;
    const int o0 = lane * 4;
    const int o1 = 256 + lane * 4;
    const int d0 = (o0 & ~63) + ((o0 >> 3) & 3) * 16 + ((o0 >> 5) & 1) * 8 + (o0 & 4);
    const int d1 = (o1 & ~63) + ((o1 >> 3) & 3) * 16 + ((o1 >> 5) & 1) * 8 + (o1 & 4);
    *(int*)(dst + d0) = pk0;
    *(int*)(dst + d1) = pk1;
}

// Kernel 2: upper-triangle 256x256 tiles of sim = Z*Z^T, fp8 MFMA 16x16x32.
// ROUND 1 lesson (counters): the 128x128 version pays a ~4-5k cycle FIXED
// stall per K-iteration (barrier + load round-trip), dwarfing the ~800cy of
// work; MX-MFMA made it worse by shrinking work-per-barrier. Fix: amortize.
// 256x256 tile, 8 waves, 64 MFMA/wave/iter (2x per-iter MFMA density/SIMD),
// 4x fewer blocks, half the staged bytes per FLOP. Double-buffered LDS
// (64 KB -> 2 blocks/CU); at ~2.5k cy/iter of compute, prefetch distance 1
// hides the L2/L3-resident loads, so plain __syncthreads (drains exactly the
// loads we need) replaces the raw-barrier/counted-vmcnt machinery safely.
// Proven R11 pieces kept verbatim: k-permuted layout, chunk^((r>>1)&3) LDS
// slot swizzle (conflict-free ds_read_b128), 16x16x32 fp8 MFMA, epilogue.
__global__ __launch_bounds__(THREADS, 4) void k_gemm(
    const unsigned char* __restrict__ zf8,
    float* __restrict__ rowsum, float* __restrict__ pos)
{
    __shared__ __align__(16) unsigned char As[2][BM * BK];  // 2 x 16 KB
    __shared__ __align__(16) unsigned char Bs[2][BM * BK];  // 2 x 16 KB

    const int tid = threadIdx.x;
    const int lane = tid & 63;
    const int w = tid >> 6;              // 0..7
    const int wr = w >> 2, wc = w & 3;   // wave grid 2 x 4: 128 rows x 64 cols
    const int q = lane >> 4, l15 = lane & 15;

    // XCD-aware bijective swizzle (528 = 8 * 66): consecutive t on one XCD
    // share B col-panels -> L2 locality.
    const int t0 = blockIdx.x;
    const int t = (t0 & 7) * (NTILES / 8) + (t0 >> 3);

    // triangular block mapping: t -> (bx >= by)
    int bi = (int)((sqrtf(8.0f * (float)t + 1.0f) - 1.0f) * 0.5f);
    while ((bi + 1) * (bi + 2) / 2 <= t) ++bi;
    while (bi * (bi + 1) / 2 > t) --bi;
    const int bx = bi;                       // col tile (larger)
    const int by = t - bi * (bi + 1) / 2;    // row tile
    const bool isDiag = (bx == by);
    const bool hasPos = (bx - by == (HALF_N / BM));   // == 16
    const int rowBase = by * BM;
    const int colBase = bx * BM;

    // staging: 16B chunks, 1024 chunks per 256x64 tile, 512 threads ->
    // 2 chunks each for A and B. LDS slot cc of row r holds source chunk
    // cc ^ ((r>>1)&3) (R8/R11-proven swizzle).
    const int ci0 = tid;            // rows 0..127
    const int ci1 = tid + THREADS;  // rows 128..255
    const int r0 = ci0 >> 2, cc0 = ci0 & 3;
    const int r1 = ci1 >> 2, cc1 = ci1 & 3;
    const int gc0 = cc0 ^ ((r0 >> 1) & 3);
    const int gc1 = cc1 ^ ((r1 >> 1) & 3);

    const unsigned char* gA0 = zf8 + (size_t)(rowBase + r0) * D_DIM + gc0 * 16;
    const unsigned char* gA1 = zf8 + (size_t)(rowBase + r1) * D_DIM + gc1 * 16;
    const unsigned char* gB0 = zf8 + (size_t)(colBase + r0) * D_DIM + gc0 * 16;
    const unsigned char* gB1 = zf8 + (size_t)(colBase + r1) * D_DIM + gc1 * 16;

    auto stage = [&](int buf, int kblk) {
        const int kb = kblk * BK;
        __builtin_amdgcn_global_load_lds((const g_u32*)(gA0 + kb), (l_u32*)&As[buf][ci0 * 16], 16, 0, 0);
        __builtin_amdgcn_global_load_lds((const g_u32*)(gA1 + kb), (l_u32*)&As[buf][ci1 * 16], 16, 0, 0);
        __builtin_amdgcn_global_load_lds((const g_u32*)(gB0 + kb), (l_u32*)&Bs[buf][ci0 * 16], 16, 0, 0);
        __builtin_amdgcn_global_load_lds((const g_u32*)(gB1 + kb), (l_u32*)&Bs[buf][ci1 * 16], 16, 0, 0);
    };

    f32x4_t acc[8][4] = {};

    stage(0, 0);

    #pragma unroll
    for (int it = 0; it < NKIT; it++) {
        const int cur = it & 1;
        // Drains this wave's vmcnt -> exactly "stage(it) complete"; barrier
        // also orders last iter's ds_reads before the stage below overwrites
        // the other buffer. Compiler-safe (no raw-barrier reorder risk).
        __syncthreads();
        if (it + 1 < NKIT) stage(cur ^ 1, it + 1);

        i64x2 aF[8], bF[4];
        #pragma unroll
        for (int i = 0; i < 8; i++) {
            const int ra = wr * 128 + i * 16 + l15;
            aF[i] = *(const i64x2*)&As[cur][ra * BK + (q ^ ((ra >> 1) & 3)) * 16];
        }
        #pragma unroll
        for (int j = 0; j < 4; j++) {
            const int rb = wc * 64 + j * 16 + l15;
            bF[j] = *(const i64x2*)&Bs[cur][rb * BK + (q ^ ((rb >> 1) & 3)) * 16];
        }
        #pragma unroll
        for (int h = 0; h < 2; h++)
            #pragma unroll
            for (int i = 0; i < 8; i++)
                #pragma unroll
                for (int j = 0; j < 4; j++)
                    acc[i][j] = __builtin_amdgcn_mfma_f32_16x16x32_fp8_fp8(
                        aF[i][h], bF[j][h], acc[i][j], 0, 0, 0);
    }

    // Epilogue. C/D layout (16x16 family): col = lane&15, row = (lane>>4)*4 + reg.
    float colacc[4] = {0.f, 0.f, 0.f, 0.f};
    #pragma unroll
    for (int i = 0; i < 8; i++) {
        #pragma unroll
        for (int r = 0; r < 4; r++) {
            const int row = rowBase + wr * 128 + i * 16 + q * 4 + r;
            float rs = 0.0f;
            #pragma unroll
            for (int j = 0; j < 4; j++) {
                const int col = colBase + wc * 64 + j * 16 + l15;
                const float c = acc[i][j][r];
                float e = __expf(c);
                if (isDiag && col == row) e = 0.0f;
                rs += e;
                colacc[j] += e;
                if (hasPos && col == row + HALF_N) { pos[row] = c; pos[col] = c; }
            }
            rs += __shfl_xor(rs, 1); rs += __shfl_xor(rs, 2);
            rs += __shfl_xor(rs, 4); rs += __shfl_xor(rs, 8);
            if (l15 == 0) atomicAdd(&rowsum[row], rs);
        }
    }
    if (!isDiag) {
        #pragma unroll
        for (int j = 0; j < 4; j++) {
            float cs = colacc[j];
            cs += __shfl_xor(cs, 16);
            cs += __shfl_xor(cs, 32);
            if (q == 0) atomicAdd(&rowsum[colBase + wc * 64 + j * 16 + l15], cs);
        }
    }
}

// Kernel 3: mean over rows of (log(rowsum) - pos) -> scalar (out pre-zeroed).
__global__ __launch_bounds__(256) void k_finalize(
    const float* __restrict__ rowsum, const float* __restrict__ pos,
    float* __restrict__ out)
{
    const int t = threadIdx.x;
    const int i = blockIdx.x * 256 + t;
    float s = logf(rowsum[i]) - pos[i];
    #pragma unroll
    for (int m = 1; m < 64; m <<= 1) s += __shfl_xor(s, m, 64);
    __shared__ float red[4];
    if ((t & 63) == 0) red[t >> 6] = s;
    __syncthreads();
    if (t == 0)
        atomicAdd(out, (red[0] + red[1] + red[2] + red[3]) * (1.0f / (float)N_TOT));
}

extern "C" void kernel_launch(void* const* d_in, const int* in_sizes, int n_in,
                              void* d_out, int out_size, void* d_ws, size_t ws_size,
                              hipStream_t stream) {
    const float* p1 = (const float*)d_in[0];
    const float* p2 = (const float*)d_in[1];

    unsigned char* zf8 = (unsigned char*)d_ws;                          // 4 MB
    float* rowsum = (float*)((char*)d_ws + (size_t)N_TOT * D_DIM);      // 32 KB
    float* pos    = rowsum + N_TOT;                                     // 32 KB
    float* outp   = (float*)d_out;

    k_normalize<<<N_TOT / 4, 256, 0, stream>>>(p1, p2, zf8, rowsum, outp);
    k_gemm<<<NTILES, THREADS, 0, stream>>>(zf8, rowsum, pos);
    k_finalize<<<N_TOT / 256, 256, 0, stream>>>(rowsum, pos, outp);
}

// Round 3
// 123.806 us; speedup vs baseline: 2.2975x; 2.2975x over previous
//
#include <hip/hip_runtime.h>
#include <hip/hip_bf16.h>
#include <math.h>

#define N_TOT 8192
#define HALF_N 4096
#define D_DIM 512
#define BM 256         // tile edge (256x256 tiles)
#define BK 64          // fp8 bytes per K-chunk; 8 K-iterations, 64B LDS rows
#define NKIT (D_DIM / BK)
#define NTILES 528     // 32*33/2 upper-triangle 256x256 tiles
#define THREADS 512    // 8 waves

typedef float f32x4_t __attribute__((ext_vector_type(4)));
typedef long long i64x2 __attribute__((ext_vector_type(2)));

typedef __attribute__((address_space(1))) unsigned int g_u32;
typedef __attribute__((address_space(3))) unsigned int l_u32;

// Kernel 1: L2-normalize rows of [p1;p2] -> fp8 e4m3 Z in k-PERMUTED layout
// (validated R9/R11): within each 64B k-block, source byte k (q=(k>>3)&3,
// h=(k>>5)&1) stored at q*16 + h*8 + (k&7). Both GEMM operands use the same
// bijection, so dot products are unaffected; a lane's two 8B MFMA k-pieces
// are one contiguous 16B chunk -> single ds_read_b128, zero bank conflicts.
__global__ __launch_bounds__(256) void k_normalize(
    const float* __restrict__ p1, const float* __restrict__ p2,
    unsigned char* __restrict__ zf8, float* __restrict__ rowsum,
    float* __restrict__ out)
{
    const int w = threadIdx.x >> 6;
    const int lane = threadIdx.x & 63;
    const int row = blockIdx.x * 4 + w;

    if (threadIdx.x < 4) rowsum[blockIdx.x * 4 + threadIdx.x] = 0.0f;
    if (blockIdx.x == 0 && threadIdx.x == 0) out[0] = 0.0f;

    const float* src = (row < HALF_N) ? p1 + (size_t)row * D_DIM
                                      : p2 + (size_t)(row - HALF_N) * D_DIM;
    float4 a = *(const float4*)(src + lane * 4);
    float4 b = *(const float4*)(src + 256 + lane * 4);
    float s = a.x*a.x + a.y*a.y + a.z*a.z + a.w*a.w
            + b.x*b.x + b.y*b.y + b.z*b.z + b.w*b.w;
    #pragma unroll
    for (int m = 1; m < 64; m <<= 1) s += __shfl_xor(s, m, 64);
    float inv = 1.0f / fmaxf(sqrtf(s), 1e-8f);

    int pk0 = __builtin_amdgcn_cvt_pk_fp8_f32(a.x * inv, a.y * inv, 0, false);
    pk0     = __builtin_amdgcn_cvt_pk_fp8_f32(a.z * inv, a.w * inv, pk0, true);
    int pk1 = __builtin_amdgcn_cvt_pk_fp8_f32(b.x * inv, b.y * inv, 0, false);
    pk1     = __builtin_amdgcn_cvt_pk_fp8_f32(b.z * inv, b.w * inv, pk1, true);

    unsigned char* dst = zf8 + (size_t)row * D_DIM;
    const int o0 = lane * 4;
    const int o1 = 256 + lane * 4;
    const int d0 = (o0 & ~63) + ((o0 >> 3) & 3) * 16 + ((o0 >> 5) & 1) * 8 + (o0 & 4);
    const int d1 = (o1 & ~63) + ((o1 >> 3) & 3) * 16 + ((o1 >> 5) & 1) * 8 + (o1 & 4);
    *(int*)(dst + d0) = pk0;
    *(int*)(dst + d1) = pk1;
}

// Kernel 2: upper-triangle 256x256 tiles of sim = Z*Z^T, fp8 MFMA 16x16x32.
// ROUND 2 lesson (counters): __launch_bounds__(512,4) capped VGPRs at 64,
// forcing the 128-float accumulator into scratch -> 710 MB of HBM scratch
// traffic (FETCH 260 MB + WRITE 450 MB), 221 us. The tile geometry itself
// was never tested. ROUND 3: identical kernel, __launch_bounds__(512,2)
// (VGPR cap 256, acc[8][4]=128 + operands + addrs ~ 200): 2 waves/SIMD,
// 1 block/CU -- the proven m201 256-square/8-wave regime.
// Proven R11 pieces kept verbatim: k-permuted layout, chunk^((r>>1)&3) LDS
// slot swizzle (conflict-free ds_read_b128), 16x16x32 fp8 MFMA, epilogue.
__global__ __launch_bounds__(THREADS, 2) void k_gemm(
    const unsigned char* __restrict__ zf8,
    float* __restrict__ rowsum, float* __restrict__ pos)
{
    __shared__ __align__(16) unsigned char As[2][BM * BK];  // 2 x 16 KB
    __shared__ __align__(16) unsigned char Bs[2][BM * BK];  // 2 x 16 KB

    const int tid = threadIdx.x;
    const int lane = tid & 63;
    const int w = tid >> 6;              // 0..7
    const int wr = w >> 2, wc = w & 3;   // wave grid 2 x 4: 128 rows x 64 cols
    const int q = lane >> 4, l15 = lane & 15;

    // XCD-aware bijective swizzle (528 = 8 * 66): consecutive t on one XCD
    // share B col-panels -> L2 locality.
    const int t0 = blockIdx.x;
    const int t = (t0 & 7) * (NTILES / 8) + (t0 >> 3);

    // triangular block mapping: t -> (bx >= by)
    int bi = (int)((sqrtf(8.0f * (float)t + 1.0f) - 1.0f) * 0.5f);
    while ((bi + 1) * (bi + 2) / 2 <= t) ++bi;
    while (bi * (bi + 1) / 2 > t) --bi;
    const int bx = bi;                       // col tile (larger)
    const int by = t - bi * (bi + 1) / 2;    // row tile
    const bool isDiag = (bx == by);
    const bool hasPos = (bx - by == (HALF_N / BM));   // == 16
    const int rowBase = by * BM;
    const int colBase = bx * BM;

    // staging: 16B chunks, 1024 chunks per 256x64 tile, 512 threads ->
    // 2 chunks each for A and B. LDS slot cc of row r holds source chunk
    // cc ^ ((r>>1)&3) (R8/R11-proven swizzle).
    const int ci0 = tid;            // rows 0..127
    const int ci1 = tid + THREADS;  // rows 128..255
    const int r0 = ci0 >> 2, cc0 = ci0 & 3;
    const int r1 = ci1 >> 2, cc1 = ci1 & 3;
    const int gc0 = cc0 ^ ((r0 >> 1) & 3);
    const int gc1 = cc1 ^ ((r1 >> 1) & 3);

    const unsigned char* gA0 = zf8 + (size_t)(rowBase + r0) * D_DIM + gc0 * 16;
    const unsigned char* gA1 = zf8 + (size_t)(rowBase + r1) * D_DIM + gc1 * 16;
    const unsigned char* gB0 = zf8 + (size_t)(colBase + r0) * D_DIM + gc0 * 16;
    const unsigned char* gB1 = zf8 + (size_t)(colBase + r1) * D_DIM + gc1 * 16;

    auto stage = [&](int buf, int kblk) {
        const int kb = kblk * BK;
        __builtin_amdgcn_global_load_lds((const g_u32*)(gA0 + kb), (l_u32*)&As[buf][ci0 * 16], 16, 0, 0);
        __builtin_amdgcn_global_load_lds((const g_u32*)(gA1 + kb), (l_u32*)&As[buf][ci1 * 16], 16, 0, 0);
        __builtin_amdgcn_global_load_lds((const g_u32*)(gB0 + kb), (l_u32*)&Bs[buf][ci0 * 16], 16, 0, 0);
        __builtin_amdgcn_global_load_lds((const g_u32*)(gB1 + kb), (l_u32*)&Bs[buf][ci1 * 16], 16, 0, 0);
    };

    f32x4_t acc[8][4] = {};

    stage(0, 0);

    #pragma unroll
    for (int it = 0; it < NKIT; it++) {
        const int cur = it & 1;
        // Drains this wave's vmcnt -> exactly "stage(it) complete"; barrier
        // also orders last iter's ds_reads before the stage below overwrites
        // the other buffer. Compiler-safe (no raw-barrier reorder risk).
        __syncthreads();
        if (it + 1 < NKIT) stage(cur ^ 1, it + 1);

        i64x2 aF[8], bF[4];
        #pragma unroll
        for (int i = 0; i < 8; i++) {
            const int ra = wr * 128 + i * 16 + l15;
            aF[i] = *(const i64x2*)&As[cur][ra * BK + (q ^ ((ra >> 1) & 3)) * 16];
        }
        #pragma unroll
        for (int j = 0; j < 4; j++) {
            const int rb = wc * 64 + j * 16 + l15;
            bF[j] = *(const i64x2*)&Bs[cur][rb * BK + (q ^ ((rb >> 1) & 3)) * 16];
        }
        #pragma unroll
        for (int h = 0; h < 2; h++)
            #pragma unroll
            for (int i = 0; i < 8; i++)
                #pragma unroll
                for (int j = 0; j < 4; j++)
                    acc[i][j] = __builtin_amdgcn_mfma_f32_16x16x32_fp8_fp8(
                        aF[i][h], bF[j][h], acc[i][j], 0, 0, 0);
    }

    // Epilogue. C/D layout (16x16 family): col = lane&15, row = (lane>>4)*4 + reg.
    float colacc[4] = {0.f, 0.f, 0.f, 0.f};
    #pragma unroll
    for (int i = 0; i < 8; i++) {
        #pragma unroll
        for (int r = 0; r < 4; r++) {
            const int row = rowBase + wr * 128 + i * 16 + q * 4 + r;
            float rs = 0.0f;
            #pragma unroll
            for (int j = 0; j < 4; j++) {
                const int col = colBase + wc * 64 + j * 16 + l15;
                const float c = acc[i][j][r];
                float e = __expf(c);
                if (isDiag && col == row) e = 0.0f;
                rs += e;
                colacc[j] += e;
                if (hasPos && col == row + HALF_N) { pos[row] = c; pos[col] = c; }
            }
            rs += __shfl_xor(rs, 1); rs += __shfl_xor(rs, 2);
            rs += __shfl_xor(rs, 4); rs += __shfl_xor(rs, 8);
            if (l15 == 0) atomicAdd(&rowsum[row], rs);
        }
    }
    if (!isDiag) {
        #pragma unroll
        for (int j = 0; j < 4; j++) {
            float cs = colacc[j];
            cs += __shfl_xor(cs, 16);
            cs += __shfl_xor(cs, 32);
            if (q == 0) atomicAdd(&rowsum[colBase + wc * 64 + j * 16 + l15], cs);
        }
    }
}

// Kernel 3: mean over rows of (log(rowsum) - pos) -> scalar (out pre-zeroed).
__global__ __launch_bounds__(256) void k_finalize(
    const float* __restrict__ rowsum, const float* __restrict__ pos,
    float* __restrict__ out)
{
    const int t = threadIdx.x;
    const int i = blockIdx.x * 256 + t;
    float s = logf(rowsum[i]) - pos[i];
    #pragma unroll
    for (int m = 1; m < 64; m <<= 1) s += __shfl_xor(s, m, 64);
    __shared__ float red[4];
    if ((t & 63) == 0) red[t >> 6] = s;
    __syncthreads();
    if (t == 0)
        atomicAdd(out, (red[0] + red[1] + red[2] + red[3]) * (1.0f / (float)N_TOT));
}

extern "C" void kernel_launch(void* const* d_in, const int* in_sizes, int n_in,
                              void* d_out, int out_size, void* d_ws, size_t ws_size,
                              hipStream_t stream) {
    const float* p1 = (const float*)d_in[0];
    const float* p2 = (const float*)d_in[1];

    unsigned char* zf8 = (unsigned char*)d_ws;                          // 4 MB
    float* rowsum = (float*)((char*)d_ws + (size_t)N_TOT * D_DIM);      // 32 KB
    float* pos    = rowsum + N_TOT;                                     // 32 KB
    float* outp   = (float*)d_out;

    k_normalize<<<N_TOT / 4, 256, 0, stream>>>(p1, p2, zf8, rowsum, outp);
    k_gemm<<<NTILES, THREADS, 0, stream>>>(zf8, rowsum, pos);
    k_finalize<<<N_TOT / 256, 256, 0, stream>>>(rowsum, pos, outp);
}

// Round 5
// 122.055 us; speedup vs baseline: 2.3305x; 1.0144x over previous
//
#include <hip/hip_runtime.h>
#include <hip/hip_bf16.h>
#include <math.h>

#define N_TOT 8192
#define HALF_N 4096
#define D_DIM 512
#define BM 256         // tile edge (256x256 tiles)
#define BK 64          // fp8 bytes per K-chunk; 8 K-iterations, 64B LDS rows
#define NKIT (D_DIM / BK)
#define NTILES 528     // 32*33/2 upper-triangle 256x256 tiles
#define THREADS 512    // 8 waves

// s_waitcnt imm: vmcnt[3:0] | expcnt<<4 | lgkmcnt<<8 (expcnt/lgkmcnt = max -> unconstrained)
#define WAIT_VM4 0xF74
#define WAIT_VM0 0xF70

typedef float f32x4_t __attribute__((ext_vector_type(4)));
typedef long long i64x2 __attribute__((ext_vector_type(2)));

typedef __attribute__((address_space(1))) unsigned int g_u32;
typedef __attribute__((address_space(3))) unsigned int l_u32;

// Kernel 1: L2-normalize rows of [p1;p2] -> fp8 e4m3 Z in k-PERMUTED layout
// (validated R9/R11): within each 64B k-block, source byte k (q=(k>>3)&3,
// h=(k>>5)&1) stored at q*16 + h*8 + (k&7). Both GEMM operands use the same
// bijection, so dot products are unaffected; a lane's two 8B MFMA k-pieces
// are one contiguous 16B chunk -> single ds_read_b128, zero bank conflicts.
__global__ __launch_bounds__(256) void k_normalize(
    const float* __restrict__ p1, const float* __restrict__ p2,
    unsigned char* __restrict__ zf8, float* __restrict__ rowsum,
    float* __restrict__ out)
{
    const int w = threadIdx.x >> 6;
    const int lane = threadIdx.x & 63;
    const int row = blockIdx.x * 4 + w;

    if (threadIdx.x < 4) rowsum[blockIdx.x * 4 + threadIdx.x] = 0.0f;
    if (blockIdx.x == 0 && threadIdx.x == 0) out[0] = 0.0f;

    const float* src = (row < HALF_N) ? p1 + (size_t)row * D_DIM
                                      : p2 + (size_t)(row - HALF_N) * D_DIM;
    float4 a = *(const float4*)(src + lane * 4);
    float4 b = *(const float4*)(src + 256 + lane * 4);
    float s = a.x*a.x + a.y*a.y + a.z*a.z + a.w*a.w
            + b.x*b.x + b.y*b.y + b.z*b.z + b.w*b.w;
    #pragma unroll
    for (int m = 1; m < 64; m <<= 1) s += __shfl_xor(s, m, 64);
    float inv = 1.0f / fmaxf(sqrtf(s), 1e-8f);

    int pk0 = __builtin_amdgcn_cvt_pk_fp8_f32(a.x * inv, a.y * inv, 0, false);
    pk0     = __builtin_amdgcn_cvt_pk_fp8_f32(a.z * inv, a.w * inv, pk0, true);
    int pk1 = __builtin_amdgcn_cvt_pk_fp8_f32(b.x * inv, b.y * inv, 0, false);
    pk1     = __builtin_amdgcn_cvt_pk_fp8_f32(b.z * inv, b.w * inv, pk1, true);

    unsigned char* dst = zf8 + (size_t)row * D_DIM;
    const int o0 = lane * 4;
    const int o1 = 256 + lane * 4;
    const int d0 = (o0 & ~63) + ((o0 >> 3) & 3) * 16 + ((o0 >> 5) & 1) * 8 + (o0 & 4);
    const int d1 = (o1 & ~63) + ((o1 >> 3) & 3) * 16 + ((o1 >> 5) & 1) * 8 + (o1 & 4);
    *(int*)(dst + d0) = pk0;
    *(int*)(dst + d1) = pk1;
}

// Kernel 2: upper-triangle 256x256 tiles of sim = Z*Z^T, fp8 MFMA 16x16x32.
// ROUND 3 lesson (counters): 256x256 tile + plain __syncthreads double-buffer
// = 69.5 us, MfmaUtil 18.8% -- the __syncthreads vmcnt(0) DRAIN at every
// K-step (waits even the just-issued prefetch) is ~72% of the critical path
// (m233 2-phase profile), and at 1 block/CU nothing hides it.
// ROUND 4/5 (R4 bench was an infra failure, resubmitted unchanged): restore
// the session-proven TRIPLE-buffer + counted `s_waitcnt vmcnt(4)` + raw
// s_barrier schedule (prefetch distance 2): the wait covers only the 4
// OLDEST loads (issued two compute-phases ago), and the next buffer's loads
// stay in flight ACROSS the barrier (T4 pattern, "never vmcnt(0) in the
// main loop"). WAW safe: stage into buf (it+2)%3 is issued after the
// barrier ending all reads of it (proven 128^2 pattern).
// + T5 setprio around the MFMA cluster. Everything else identical to R3:
// k-permuted layout, chunk^((r>>1)&3) LDS slot swizzle (0 conflicts),
// launch_bounds(512,2) (R2 lesson: (512,4) forced acc into scratch).
__global__ __launch_bounds__(THREADS, 2) void k_gemm(
    const unsigned char* __restrict__ zf8,
    float* __restrict__ rowsum, float* __restrict__ pos)
{
    __shared__ __align__(16) unsigned char As[3][BM * BK];  // 3 x 16 KB
    __shared__ __align__(16) unsigned char Bs[3][BM * BK];  // 3 x 16 KB

    const int tid = threadIdx.x;
    const int lane = tid & 63;
    const int w = tid >> 6;              // 0..7
    const int wr = w >> 2, wc = w & 3;   // wave grid 2 x 4: 128 rows x 64 cols
    const int q = lane >> 4, l15 = lane & 15;

    // XCD-aware bijective swizzle (528 = 8 * 66): consecutive t on one XCD
    // share panels -> L2 locality.
    const int t0 = blockIdx.x;
    const int t = (t0 & 7) * (NTILES / 8) + (t0 >> 3);

    // triangular block mapping: t -> (bx >= by)
    int bi = (int)((sqrtf(8.0f * (float)t + 1.0f) - 1.0f) * 0.5f);
    while ((bi + 1) * (bi + 2) / 2 <= t) ++bi;
    while (bi * (bi + 1) / 2 > t) --bi;
    const int bx = bi;                       // col tile (larger)
    const int by = t - bi * (bi + 1) / 2;    // row tile
    const bool isDiag = (bx == by);
    const bool hasPos = (bx - by == (HALF_N / BM));   // == 16
    const int rowBase = by * BM;
    const int colBase = bx * BM;

    // staging: 16B chunks, 1024 chunks per 256x64 tile, 512 threads ->
    // 2 chunks each for A and B. LDS slot cc of row r holds source chunk
    // cc ^ ((r>>1)&3) (R8/R11-proven swizzle).
    const int ci0 = tid;            // rows 0..127
    const int ci1 = tid + THREADS;  // rows 128..255
    const int r0 = ci0 >> 2, cc0 = ci0 & 3;
    const int r1 = ci1 >> 2, cc1 = ci1 & 3;
    const int gc0 = cc0 ^ ((r0 >> 1) & 3);
    const int gc1 = cc1 ^ ((r1 >> 1) & 3);

    const unsigned char* gA0 = zf8 + (size_t)(rowBase + r0) * D_DIM + gc0 * 16;
    const unsigned char* gA1 = zf8 + (size_t)(rowBase + r1) * D_DIM + gc1 * 16;
    const unsigned char* gB0 = zf8 + (size_t)(colBase + r0) * D_DIM + gc0 * 16;
    const unsigned char* gB1 = zf8 + (size_t)(colBase + r1) * D_DIM + gc1 * 16;

    auto stage = [&](int buf, int kblk) {
        const int kb = kblk * BK;
        __builtin_amdgcn_global_load_lds((const g_u32*)(gA0 + kb), (l_u32*)&As[buf][ci0 * 16], 16, 0, 0);
        __builtin_amdgcn_global_load_lds((const g_u32*)(gA1 + kb), (l_u32*)&As[buf][ci1 * 16], 16, 0, 0);
        __builtin_amdgcn_global_load_lds((const g_u32*)(gB0 + kb), (l_u32*)&Bs[buf][ci0 * 16], 16, 0, 0);
        __builtin_amdgcn_global_load_lds((const g_u32*)(gB1 + kb), (l_u32*)&Bs[buf][ci1 * 16], 16, 0, 0);
    };

    f32x4_t acc[8][4] = {};

    stage(0, 0);   // 4 vm ops (oldest)
    stage(1, 1);   // 4 vm ops

    #pragma unroll
    for (int it = 0; it < NKIT; it++) {
        const int cur = it % 3;
        // wait ONLY the 4 oldest loads (= buf[cur], issued 2 iterations ago);
        // keep next iter's 4 in flight across the barrier.
        if (it + 1 < NKIT) __builtin_amdgcn_s_waitcnt(WAIT_VM4);
        else               __builtin_amdgcn_s_waitcnt(WAIT_VM0);
        __builtin_amdgcn_s_barrier();

        if (it + 2 < NKIT) stage((it + 2) % 3, it + 2);

        i64x2 aF[8], bF[4];
        #pragma unroll
        for (int i = 0; i < 8; i++) {
            const int ra = wr * 128 + i * 16 + l15;
            aF[i] = *(const i64x2*)&As[cur][ra * BK + (q ^ ((ra >> 1) & 3)) * 16];
        }
        #pragma unroll
        for (int j = 0; j < 4; j++) {
            const int rb = wc * 64 + j * 16 + l15;
            bF[j] = *(const i64x2*)&Bs[cur][rb * BK + (q ^ ((rb >> 1) & 3)) * 16];
        }
        __builtin_amdgcn_s_setprio(1);
        #pragma unroll
        for (int h = 0; h < 2; h++)
            #pragma unroll
            for (int i = 0; i < 8; i++)
                #pragma unroll
                for (int j = 0; j < 4; j++)
                    acc[i][j] = __builtin_amdgcn_mfma_f32_16x16x32_fp8_fp8(
                        aF[i][h], bF[j][h], acc[i][j], 0, 0, 0);
        __builtin_amdgcn_s_setprio(0);
    }

    // Epilogue. C/D layout (16x16 family): col = lane&15, row = (lane>>4)*4 + reg.
    float colacc[4] = {0.f, 0.f, 0.f, 0.f};
    #pragma unroll
    for (int i = 0; i < 8; i++) {
        #pragma unroll
        for (int r = 0; r < 4; r++) {
            const int row = rowBase + wr * 128 + i * 16 + q * 4 + r;
            float rs = 0.0f;
            #pragma unroll
            for (int j = 0; j < 4; j++) {
                const int col = colBase + wc * 64 + j * 16 + l15;
                const float c = acc[i][j][r];
                float e = __expf(c);
                if (isDiag && col == row) e = 0.0f;
                rs += e;
                colacc[j] += e;
                if (hasPos && col == row + HALF_N) { pos[row] = c; pos[col] = c; }
            }
            rs += __shfl_xor(rs, 1); rs += __shfl_xor(rs, 2);
            rs += __shfl_xor(rs, 4); rs += __shfl_xor(rs, 8);
            if (l15 == 0) atomicAdd(&rowsum[row], rs);
        }
    }
    if (!isDiag) {
        #pragma unroll
        for (int j = 0; j < 4; j++) {
            float cs = colacc[j];
            cs += __shfl_xor(cs, 16);
            cs += __shfl_xor(cs, 32);
            if (q == 0) atomicAdd(&rowsum[colBase + wc * 64 + j * 16 + l15], cs);
        }
    }
}

// Kernel 3: mean over rows of (log(rowsum) - pos) -> scalar (out pre-zeroed).
__global__ __launch_bounds__(256) void k_finalize(
    const float* __restrict__ rowsum, const float* __restrict__ pos,
    float* __restrict__ out)
{
    const int t = threadIdx.x;
    const int i = blockIdx.x * 256 + t;
    float s = logf(rowsum[i]) - pos[i];
    #pragma unroll
    for (int m = 1; m < 64; m <<= 1) s += __shfl_xor(s, m, 64);
    __shared__ float red[4];
    if ((t & 63) == 0) red[t >> 6] = s;
    __syncthreads();
    if (t == 0)
        atomicAdd(out, (red[0] + red[1] + red[2] + red[3]) * (1.0f / (float)N_TOT));
}

extern "C" void kernel_launch(void* const* d_in, const int* in_sizes, int n_in,
                              void* d_out, int out_size, void* d_ws, size_t ws_size,
                              hipStream_t stream) {
    const float* p1 = (const float*)d_in[0];
    const float* p2 = (const float*)d_in[1];

    unsigned char* zf8 = (unsigned char*)d_ws;                          // 4 MB
    float* rowsum = (float*)((char*)d_ws + (size_t)N_TOT * D_DIM);      // 32 KB
    float* pos    = rowsum + N_TOT;                                     // 32 KB
    float* outp   = (float*)d_out;

    k_normalize<<<N_TOT / 4, 256, 0, stream>>>(p1, p2, zf8, rowsum, outp);
    k_gemm<<<NTILES, THREADS, 0, stream>>>(zf8, rowsum, pos);
    k_finalize<<<N_TOT / 256, 256, 0, stream>>>(rowsum, pos, outp);
}